// Round 3
// baseline (22053.358 us; speedup 1.0000x reference)
//
#include <hip/hip_runtime.h>
#include <math.h>

#define Bn 4
#define Ln 4096
#define Dn 1024
#define DIn 4096
#define Mn 8
#define Rn (Bn*Ln)          // 16384 rows
#define CHUNK 2048
#define NCH (Rn/CHUNK)      // 8 chunks
#define NSTEP 4
#define THRc 0.5f
#define EPSc 1e-6f

// ---------- block-wide reductions (block = 256 = 4 waves) ----------
__device__ __forceinline__ float bsum(float v, float* sb) {
    #pragma unroll
    for (int off = 32; off; off >>= 1) v += __shfl_down(v, off);
    int wave = threadIdx.x >> 6, lane = threadIdx.x & 63;
    if (lane == 0) sb[wave] = v;
    __syncthreads();
    float r = sb[0] + sb[1] + sb[2] + sb[3];
    __syncthreads();
    return r;
}

__device__ __forceinline__ float bmax(float v, float* sb) {
    #pragma unroll
    for (int off = 32; off; off >>= 1) v = fmaxf(v, __shfl_down(v, off));
    int wave = threadIdx.x >> 6, lane = threadIdx.x & 63;
    if (lane == 0) sb[wave] = v;
    __syncthreads();
    float r = fmaxf(fmaxf(sb[0], sb[1]), fmaxf(sb[2], sb[3]));
    __syncthreads();
    return r;
}

// ---------- init: hidden = x, acc = 0, cum = 0 ----------
__global__ __launch_bounds__(256)
void init_kernel(const float* __restrict__ x, float* __restrict__ hidden,
                 float* __restrict__ acc, float* __restrict__ cum) {
    size_t i = (size_t)blockIdx.x * 256 + threadIdx.x;   // quad index over Rn*Dn/4
    float4 v = ((const float4*)x)[i];
    ((float4*)hidden)[i] = v;
    float4 z = {0.f, 0.f, 0.f, 0.f};
    ((float4*)acc)[i] = z;
    if (i < Rn) cum[i] = 0.f;
}

// ---------- per-row: LayerNorm(hidden) -> n ; normalized entropy(hidden) -> ent ----------
__global__ __launch_bounds__(256)
void ln_ent_kernel(const float* __restrict__ hidden,
                   const float* __restrict__ g1, const float* __restrict__ b1,
                   float* __restrict__ n_out, float* __restrict__ ent_out) {
    __shared__ float sb[4];
    int row = blockIdx.x;
    int t = threadIdx.x;
    const float* h = hidden + (size_t)row * Dn;
    float4 hv = ((const float4*)h)[t];
    float vals[4] = {hv.x, hv.y, hv.z, hv.w};
    float s = 0.f, s2 = 0.f, mx = -INFINITY;
    #pragma unroll
    for (int i = 0; i < 4; i++) { s += vals[i]; s2 += vals[i]*vals[i]; mx = fmaxf(mx, vals[i]); }
    s  = bsum(s,  sb);
    s2 = bsum(s2, sb);
    mx = bmax(mx, sb);
    float mean = s * (1.f / Dn);
    float var  = s2 * (1.f / Dn) - mean * mean;
    float rstd = rsqrtf(var + EPSc);
    // entropy of softmax(hidden): ent = (mx + log Z - S/Z) / log(D)
    float Z = 0.f, S = 0.f;
    #pragma unroll
    for (int i = 0; i < 4; i++) { float e = expf(vals[i] - mx); Z += e; S += e * vals[i]; }
    Z = bsum(Z, sb);
    S = bsum(S, sb);
    if (t == 0) {
        ent_out[row] = (mx + logf(Z) - S / Z) * (1.0f / logf((float)Dn));
    }
    float4 g = ((const float4*)g1)[t];
    float4 bb = ((const float4*)b1)[t];
    float4 o;
    o.x = (vals[0] - mean) * rstd * g.x + bb.x;
    o.y = (vals[1] - mean) * rstd * g.y + bb.y;
    o.z = (vals[2] - mean) * rstd * g.z + bb.z;
    o.w = (vals[3] - mean) * rstd * g.w + bb.w;
    ((float4*)(n_out + (size_t)row * Dn))[t] = o;
}

// ---------- tiled fp32 GEMM: C[Mr,N] = epilogue(A[Mr,K] @ B[K,N] + bias) ----------
// mode 0: C = gelu_exact(AB + bias);  mode 1: C = res + AB + bias
__global__ __launch_bounds__(256)
void gemm_kernel(const float* __restrict__ A, const float* __restrict__ Bm,
                 const float* __restrict__ bias, const float* __restrict__ res,
                 float* __restrict__ C, int Mr, int N, int K, int mode) {
    __shared__ float As[16][64];   // [k][m]
    __shared__ float Bs[16][64];   // [k][n]
    int tid = threadIdx.x;
    int tx = tid & 15, ty = tid >> 4;
    int m0 = blockIdx.y * 64, n0 = blockIdx.x * 64;
    int my0 = ty * 4, nx0 = tx * 4;
    float acc[4][4] = {};
    int ar = tid >> 2, ak = (tid & 3) << 2;   // A stage: row ar (0..63), k-quad ak
    int bk = tid >> 4, bn = (tid & 15) << 2;  // B stage: k row bk (0..15), n-quad bn
    for (int k0 = 0; k0 < K; k0 += 16) {
        float4 av = *(const float4*)(A + (size_t)(m0 + ar) * K + k0 + ak);
        float4 bv = *(const float4*)(Bm + (size_t)(k0 + bk) * N + n0 + bn);
        As[ak + 0][ar] = av.x;
        As[ak + 1][ar] = av.y;
        As[ak + 2][ar] = av.z;
        As[ak + 3][ar] = av.w;
        *(float4*)&Bs[bk][bn] = bv;
        __syncthreads();
        #pragma unroll
        for (int k = 0; k < 16; k++) {
            float4 a4 = *(const float4*)&As[k][my0];
            float4 b4 = *(const float4*)&Bs[k][nx0];
            acc[0][0] += a4.x*b4.x; acc[0][1] += a4.x*b4.y; acc[0][2] += a4.x*b4.z; acc[0][3] += a4.x*b4.w;
            acc[1][0] += a4.y*b4.x; acc[1][1] += a4.y*b4.y; acc[1][2] += a4.y*b4.z; acc[1][3] += a4.y*b4.w;
            acc[2][0] += a4.z*b4.x; acc[2][1] += a4.z*b4.y; acc[2][2] += a4.z*b4.z; acc[2][3] += a4.z*b4.w;
            acc[3][0] += a4.w*b4.x; acc[3][1] += a4.w*b4.y; acc[3][2] += a4.w*b4.z; acc[3][3] += a4.w*b4.w;
        }
        __syncthreads();
    }
    float4 bb = *(const float4*)(bias + n0 + nx0);
    #pragma unroll
    for (int i = 0; i < 4; i++) {
        size_t off = (size_t)(m0 + my0 + i) * N + n0 + nx0;
        float4 c;
        c.x = acc[i][0] + bb.x; c.y = acc[i][1] + bb.y;
        c.z = acc[i][2] + bb.z; c.w = acc[i][3] + bb.w;
        if (mode == 0) {
            c.x = 0.5f * c.x * (1.0f + erff(c.x * 0.70710678118654752f));
            c.y = 0.5f * c.y * (1.0f + erff(c.y * 0.70710678118654752f));
            c.z = 0.5f * c.z * (1.0f + erff(c.z * 0.70710678118654752f));
            c.w = 0.5f * c.w * (1.0f + erff(c.w * 0.70710678118654752f));
        } else {
            float4 r = *(const float4*)(res + off);
            c.x += r.x; c.y += r.y; c.z += r.z; c.w += r.w;
        }
        *(float4*)(C + off) = c;
    }
}

// ---------- scores[r,m] = h_new[r,:] @ W_comp[:,m] + b_comp[m] ----------
__global__ __launch_bounds__(256)
void scores_kernel(const float* __restrict__ h, const float* __restrict__ Wc,
                   const float* __restrict__ bc, float* __restrict__ scores) {
    int row = blockIdx.x;
    int t = threadIdx.x;
    float acc[Mn] = {};
    const float* hr = h + (size_t)row * Dn;
    for (int d = t; d < Dn; d += 256) {
        float hv = hr[d];
        const float* w = Wc + (size_t)d * Mn;
        #pragma unroll
        for (int m = 0; m < Mn; m++) acc[m] += hv * w[m];
    }
    __shared__ float red[Mn][4];
    int wave = t >> 6, lane = t & 63;
    #pragma unroll
    for (int m = 0; m < Mn; m++) {
        float v = acc[m];
        #pragma unroll
        for (int off = 32; off; off >>= 1) v += __shfl_down(v, off);
        if (lane == 0) red[m][wave] = v;
    }
    __syncthreads();
    if (t < Mn) {
        float v = red[t][0] + red[t][1] + red[t][2] + red[t][3];
        scores[(size_t)row * Mn + t] = v + bc[t];
    }
}

// ---------- softmax over L (axis=1) per (b,m) ----------
__global__ __launch_bounds__(256)
void softmaxL_kernel(const float* __restrict__ scores, float* __restrict__ wL) {
    __shared__ float sb[4];
    int b = blockIdx.x / Mn, m = blockIdx.x % Mn;
    int t = threadIdx.x;
    const float* s = scores + (size_t)b * Ln * Mn + m;
    float mx = -INFINITY;
    for (int l = t; l < Ln; l += 256) mx = fmaxf(mx, s[(size_t)l * Mn]);
    mx = bmax(mx, sb);
    float z = 0.f;
    for (int l = t; l < Ln; l += 256) z += expf(s[(size_t)l * Mn] - mx);
    z = bsum(z, sb);
    float inv = 1.0f / z;
    float* w = wL + (size_t)b * Ln * Mn + m;
    for (int l = t; l < Ln; l += 256) w[(size_t)l * Mn] = expf(s[(size_t)l * Mn] - mx) * inv;
}

// ---------- memory partials: mpart[lc][b][m][d] = sum_{l in chunk lc} wL[b,l,m]*h[b,l,d] ----------
__global__ __launch_bounds__(256)
void memory_kernel(const float* __restrict__ h, const float* __restrict__ wL,
                   float* __restrict__ mpart) {
    int bid = blockIdx.x;                 // Bn * (Dn/256) * (Ln/512) = 128 blocks
    int lc = bid & 7;
    int dc = (bid >> 3) & 3;
    int b  = bid >> 5;
    int t = threadIdx.x;
    int d = dc * 256 + t;
    int l0 = lc * 512;
    float acc[Mn] = {};
    const float* hp = h + ((size_t)b * Ln + l0) * Dn + d;
    const float* wp = wL + ((size_t)b * Ln + l0) * Mn;
    for (int l = 0; l < 512; l++) {
        float hv = hp[(size_t)l * Dn];
        float4 w0 = *(const float4*)(wp + (size_t)l * Mn);
        float4 w1 = *(const float4*)(wp + (size_t)l * Mn + 4);
        acc[0] += w0.x * hv; acc[1] += w0.y * hv; acc[2] += w0.z * hv; acc[3] += w0.w * hv;
        acc[4] += w1.x * hv; acc[5] += w1.y * hv; acc[6] += w1.z * hv; acc[7] += w1.w * hv;
    }
    #pragma unroll
    for (int m = 0; m < Mn; m++)
        mpart[(((size_t)lc * Bn + b) * Mn + m) * Dn + d] = acc[m];
}

// ---------- reduce partials: mem[b][m][d] = sum_lc mpart[lc][b][m][d] ----------
__global__ __launch_bounds__(256)
void memreduce_kernel(const float* __restrict__ mpart, float* __restrict__ mem) {
    int i = blockIdx.x * 256 + threadIdx.x;   // over Bn*Mn*Dn = 32768
    float s = 0.f;
    #pragma unroll
    for (int lc = 0; lc < 8; lc++) s += mpart[(size_t)lc * Bn * Mn * Dn + i];
    mem[i] = s;
}

// ---------- ctx[r,d] = sum_m softmax_M(scores[r,:])[m] * memory[b,m,d] ----------
__global__ __launch_bounds__(256)
void ctx_kernel(const float* __restrict__ scores, const float* __restrict__ mem,
                float* __restrict__ ctx, int bidx) {
    int row = blockIdx.x;    // local to chunk
    int t = threadIdx.x;
    const float* s = scores + (size_t)row * Mn;
    float sm[Mn];
    float mx = -INFINITY;
    #pragma unroll
    for (int m = 0; m < Mn; m++) mx = fmaxf(mx, s[m]);
    float z = 0.f;
    #pragma unroll
    for (int m = 0; m < Mn; m++) { sm[m] = expf(s[m] - mx); z += sm[m]; }
    float inv = 1.0f / z;
    float4 acc = {0.f, 0.f, 0.f, 0.f};
    #pragma unroll
    for (int m = 0; m < Mn; m++) {
        float w = sm[m] * inv;
        float4 mv = ((const float4*)(mem + ((size_t)bidx * Mn + m) * Dn))[t];
        acc.x += w * mv.x; acc.y += w * mv.y; acc.z += w * mv.z; acc.w += w * mv.w;
    }
    ((float4*)(ctx + (size_t)row * Dn))[t] = acc;
}

// ---------- entropy gate + ACT halting; hidden <- selected h_new ----------
__global__ __launch_bounds__(256)
void gate_halt_kernel(const float* __restrict__ h_new, float* __restrict__ hidden,
                      const float* __restrict__ ent, const float* __restrict__ Wh,
                      const float* __restrict__ bh, float* __restrict__ acc,
                      float* __restrict__ cum) {
    __shared__ float sb[4];
    int row = blockIdx.x;
    int t = threadIdx.x;
    bool upd = ent[row] > THRc;
    const float* src = (upd ? h_new : hidden) + (size_t)row * Dn;
    float4 hv = ((const float4*)src)[t];
    float4 wv = ((const float4*)Wh)[t];
    float dot = hv.x*wv.x + hv.y*wv.y + hv.z*wv.z + hv.w*wv.w;
    dot = bsum(dot, sb);
    float p = 1.0f / (1.0f + expf(-(dot + bh[0])));
    float c = cum[row];
    float w = p * (1.0f - c);
    float4 a = ((const float4*)(acc + (size_t)row * Dn))[t];
    a.x += w * hv.x; a.y += w * hv.y; a.z += w * hv.z; a.w += w * hv.w;
    ((float4*)(acc + (size_t)row * Dn))[t] = a;
    ((float4*)(hidden + (size_t)row * Dn))[t] = hv;
    __syncthreads();                 // all waves read cum[row] before lane0 overwrites it
    if (t == 0) cum[row] = c + w;
}

// ---------- final: out = LN(acc + (1-cum)*hidden, g2, b2) ----------
__global__ __launch_bounds__(256)
void final_ln_kernel(const float* __restrict__ acc, const float* __restrict__ cum,
                     const float* __restrict__ hidden,
                     const float* __restrict__ g2, const float* __restrict__ b2,
                     float* __restrict__ out) {
    __shared__ float sb[4];
    int row = blockIdx.x;
    int t = threadIdx.x;
    float c = 1.0f - cum[row];
    float4 a = ((const float4*)(acc + (size_t)row * Dn))[t];
    float4 h = ((const float4*)(hidden + (size_t)row * Dn))[t];
    float vals[4];
    vals[0] = a.x + c * h.x; vals[1] = a.y + c * h.y;
    vals[2] = a.z + c * h.z; vals[3] = a.w + c * h.w;
    float s = 0.f, s2 = 0.f;
    #pragma unroll
    for (int i = 0; i < 4; i++) { s += vals[i]; s2 += vals[i]*vals[i]; }
    s  = bsum(s,  sb);
    s2 = bsum(s2, sb);
    float mean = s * (1.f / Dn);
    float var  = s2 * (1.f / Dn) - mean * mean;
    float rstd = rsqrtf(var + EPSc);
    float4 g = ((const float4*)g2)[t];
    float4 bb = ((const float4*)b2)[t];
    float4 o;
    o.x = (vals[0] - mean) * rstd * g.x + bb.x;
    o.y = (vals[1] - mean) * rstd * g.y + bb.y;
    o.z = (vals[2] - mean) * rstd * g.z + bb.z;
    o.w = (vals[3] - mean) * rstd * g.w + bb.w;
    ((float4*)(out + (size_t)row * Dn))[t] = o;
}

extern "C" void kernel_launch(void* const* d_in, const int* in_sizes, int n_in,
                              void* d_out, int out_size, void* d_ws, size_t ws_size,
                              hipStream_t stream) {
    (void)in_sizes; (void)n_in; (void)out_size; (void)ws_size;
    const float* x      = (const float*)d_in[0];
    const float* g1     = (const float*)d_in[1];
    const float* b1     = (const float*)d_in[2];
    const float* W_up   = (const float*)d_in[3];
    const float* b_up   = (const float*)d_in[4];
    const float* W_down = (const float*)d_in[5];
    const float* b_down = (const float*)d_in[6];
    const float* W_halt = (const float*)d_in[7];
    const float* b_halt = (const float*)d_in[8];
    const float* W_comp = (const float*)d_in[9];
    const float* b_comp = (const float*)d_in[10];
    const float* W_attn = (const float*)d_in[11];
    const float* b_attn = (const float*)d_in[12];
    const float* g2     = (const float*)d_in[13];
    const float* b2     = (const float*)d_in[14];
    float* out = (float*)d_out;

    // ws layout — total ~242 MB (round 2's 252 MB ran without fault; round 1's 289 MB crashed)
    float* ws = (float*)d_ws;
    size_t off = 0;
    float* hidden = ws + off; off += (size_t)Rn * Dn;       // 64 MB
    float* accb   = ws + off; off += (size_t)Rn * Dn;       // 64 MB
    float* hnew   = ws + off; off += (size_t)Rn * Dn;       // 64 MB
    float* nchunk = ws + off; off += (size_t)CHUNK * Dn;    //  8 MB
    float* ubuf   = ws + off; off += (size_t)CHUNK * DIn;   // 32 MB
    float* ctxch  = ws + off; off += (size_t)CHUNK * Dn;    //  8 MB
    float* scores = ws + off; off += (size_t)Rn * Mn;       // 0.5 MB
    float* wL     = ws + off; off += (size_t)Rn * Mn;       // 0.5 MB
    float* mpart  = ws + off; off += (size_t)8 * Bn * Mn * Dn;  // 1 MB
    float* memb   = ws + off; off += (size_t)Bn * Mn * Dn;  // 0.125 MB
    float* ent    = ws + off; off += Rn;
    float* cum    = ws + off; off += Rn;

    init_kernel<<<(Rn * Dn / 4) / 256, 256, 0, stream>>>(x, hidden, accb, cum);

    for (int s = 0; s < NSTEP; ++s) {
        for (int c = 0; c < NCH; ++c) {
            ln_ent_kernel<<<CHUNK, 256, 0, stream>>>(
                hidden + (size_t)c * CHUNK * Dn, g1, b1, nchunk, ent + (size_t)c * CHUNK);
            gemm_kernel<<<dim3(DIn / 64, CHUNK / 64), 256, 0, stream>>>(
                nchunk, W_up, b_up, nullptr, ubuf, CHUNK, DIn, Dn, 0);
            gemm_kernel<<<dim3(Dn / 64, CHUNK / 64), 256, 0, stream>>>(
                ubuf, W_down, b_down, hidden + (size_t)c * CHUNK * Dn,
                hnew + (size_t)c * CHUNK * Dn, CHUNK, Dn, DIn, 1);
        }
        scores_kernel<<<Rn, 256, 0, stream>>>(hnew, W_comp, b_comp, scores);
        softmaxL_kernel<<<Bn * Mn, 256, 0, stream>>>(scores, wL);
        memory_kernel<<<Bn * (Dn / 256) * (Ln / 512), 256, 0, stream>>>(hnew, wL, mpart);
        memreduce_kernel<<<(Bn * Mn * Dn) / 256, 256, 0, stream>>>(mpart, memb);
        for (int c = 0; c < NCH; ++c) {
            ctx_kernel<<<CHUNK, 256, 0, stream>>>(
                scores + (size_t)c * CHUNK * Mn, memb, ctxch, (c * CHUNK) / Ln);
            gemm_kernel<<<dim3(Dn / 64, CHUNK / 64), 256, 0, stream>>>(
                ctxch, W_attn, b_attn, hnew + (size_t)c * CHUNK * Dn,
                hnew + (size_t)c * CHUNK * Dn, CHUNK, Dn, Dn, 1);
        }
        gate_halt_kernel<<<Rn, 256, 0, stream>>>(hnew, hidden, ent, W_halt, b_halt, accb, cum);
    }

    final_ln_kernel<<<Rn, 256, 0, stream>>>(accb, cum, hidden, g2, b2, out);
}

// Round 6
// 8530.772 us; speedup vs baseline: 2.5852x; 2.5852x over previous
//
#include <hip/hip_runtime.h>
#include <math.h>

#define Bn 4
#define Ln 4096
#define Dn 1024
#define DIn 4096
#define Mn 8
#define Rn (Bn*Ln)          // 16384 rows
#define CHUNK 2048
#define NCH (Rn/CHUNK)      // 8 chunks
#define NSTEP 4
#define THRc 0.5f
#define EPSc 1e-6f

typedef unsigned short bfu;
typedef _Float16 f16;
typedef __attribute__((ext_vector_type(8))) _Float16 f16x8;  // MFMA A/B frag (4 VGPRs)
typedef __attribute__((ext_vector_type(4))) _Float16 f16x4;
typedef __attribute__((ext_vector_type(4))) float f32x4;     // MFMA C/D frag

// ---------- helpers ----------
__device__ __forceinline__ bfu f2b(float f) {
    union { float f; unsigned i; } v; v.f = f;
    unsigned r = v.i + 0x7FFFu + ((v.i >> 16) & 1u);  // RNE
    return (bfu)(r >> 16);
}
__device__ __forceinline__ float b2f(bfu u) {
    union { float f; unsigned i; } v; v.i = ((unsigned)u) << 16; return v.f;
}
__device__ __forceinline__ void split2(float x, f16& h, f16& l) {
    h = (f16)x; l = (f16)(x - (float)h);
}

// ---------- block-wide reductions (block = 256 = 4 waves) ----------
__device__ __forceinline__ float bsum(float v, float* sb) {
    #pragma unroll
    for (int off = 32; off; off >>= 1) v += __shfl_down(v, off);
    int wave = threadIdx.x >> 6, lane = threadIdx.x & 63;
    if (lane == 0) sb[wave] = v;
    __syncthreads();
    float r = sb[0] + sb[1] + sb[2] + sb[3];
    __syncthreads();
    return r;
}

__device__ __forceinline__ float bmax(float v, float* sb) {
    #pragma unroll
    for (int off = 32; off; off >>= 1) v = fmaxf(v, __shfl_down(v, off));
    int wave = threadIdx.x >> 6, lane = threadIdx.x & 63;
    if (lane == 0) sb[wave] = v;
    __syncthreads();
    float r = fmaxf(fmaxf(sb[0], sb[1]), fmaxf(sb[2], sb[3]));
    __syncthreads();
    return r;
}

// ---------- init: hidden = x, acc(bf16) = 0, cum = 0 ----------
__global__ __launch_bounds__(256)
void init_kernel(const float* __restrict__ x, float* __restrict__ hidden,
                 bfu* __restrict__ acc, float* __restrict__ cum) {
    size_t i = (size_t)blockIdx.x * 256 + threadIdx.x;   // quad index over Rn*Dn/4
    float4 v = ((const float4*)x)[i];
    ((float4*)hidden)[i] = v;
    ushort4 z = {0, 0, 0, 0};
    *(ushort4*)(acc + i * 4) = z;
    if (i < Rn) cum[i] = 0.f;
}

// ---------- weight convert+transpose+split: Wh/Wl[n][k] = split(W[k][n]) ----------
__global__ __launch_bounds__(256)
void transpose_cvt_kernel(const float* __restrict__ W, f16* __restrict__ Wh,
                          f16* __restrict__ Wl, int K, int N) {
    __shared__ float tile[32][33];
    int k0 = blockIdx.y * 32, n0 = blockIdx.x * 32;
    int t = threadIdx.x;
    int r = t >> 5, c = t & 31;    // r 0..7, c 0..31
    #pragma unroll
    for (int j = 0; j < 4; j++)
        tile[r + j * 8][c] = W[(size_t)(k0 + r + j * 8) * N + n0 + c];
    __syncthreads();
    #pragma unroll
    for (int j = 0; j < 4; j++) {
        float v = tile[c][r + j * 8];
        size_t idx = (size_t)(n0 + r + j * 8) * K + k0 + c;
        f16 h, l; split2(v, h, l);
        Wh[idx] = h; Wl[idx] = l;
    }
}

// ---------- per-row: LayerNorm(hidden) -> nh/nl (f16 split) ; entropy(hidden) -> ent ----------
__global__ __launch_bounds__(256)
void ln_ent_kernel(const float* __restrict__ hidden,
                   const float* __restrict__ g1, const float* __restrict__ b1,
                   f16* __restrict__ nh, f16* __restrict__ nl, float* __restrict__ ent_out) {
    __shared__ float sb[4];
    int row = blockIdx.x;
    int t = threadIdx.x;
    const float* h = hidden + (size_t)row * Dn;
    float4 hv = ((const float4*)h)[t];
    float vals[4] = {hv.x, hv.y, hv.z, hv.w};
    float s = 0.f, s2 = 0.f, mx = -INFINITY;
    #pragma unroll
    for (int i = 0; i < 4; i++) { s += vals[i]; s2 += vals[i]*vals[i]; mx = fmaxf(mx, vals[i]); }
    s  = bsum(s,  sb);
    s2 = bsum(s2, sb);
    mx = bmax(mx, sb);
    float mean = s * (1.f / Dn);
    float var  = s2 * (1.f / Dn) - mean * mean;
    float rstd = rsqrtf(var + EPSc);
    float Z = 0.f, S = 0.f;
    #pragma unroll
    for (int i = 0; i < 4; i++) { float e = expf(vals[i] - mx); Z += e; S += e * vals[i]; }
    Z = bsum(Z, sb);
    S = bsum(S, sb);
    if (t == 0) {
        ent_out[row] = (mx + logf(Z) - S / Z) * (1.0f / logf((float)Dn));
    }
    float4 g = ((const float4*)g1)[t];
    float4 bb = ((const float4*)b1)[t];
    float o[4];
    o[0] = (vals[0] - mean) * rstd * g.x + bb.x;
    o[1] = (vals[1] - mean) * rstd * g.y + bb.y;
    o[2] = (vals[2] - mean) * rstd * g.z + bb.z;
    o[3] = (vals[3] - mean) * rstd * g.w + bb.w;
    f16x4 oh, ol;
    #pragma unroll
    for (int i = 0; i < 4; i++) { f16 hh, ll; split2(o[i], hh, ll); oh[i] = hh; ol[i] = ll; }
    *(f16x4*)(nh + (size_t)row * Dn + t * 4) = oh;
    *(f16x4*)(nl + (size_t)row * Dn + t * 4) = ol;
}

// ---------- split-fp16 MFMA GEMM: C = epi(A @ Bt^T + bias), A=Ah+Al, Bt=Bh+Bl ----------
// TM x TN tile, BK=32, 256 threads = 4 waves (2x2), wave tile (TM/2)x(TN/2).
// MODE 0: gelu -> split f16 (C0=h, C1=l).  MODE 1: C0(fp32) = res + v.
template<int MODE, int TM, int TN>
__global__ __launch_bounds__(256)
void gemm_f16s(const f16* __restrict__ Ah, const f16* __restrict__ Al,
               const f16* __restrict__ Bh, const f16* __restrict__ Bl,
               const float* __restrict__ bias, const float* __restrict__ res,
               void* __restrict__ C0, void* __restrict__ C1, int N, int K) {
    constexpr int MF = TM / 32;       // 16x16 m-frags per wave
    constexpr int NF = TN / 32;
    constexpr int AI = TM / 64;       // staging instrs per wave per A buffer
    constexpr int BI = TN / 64;
    __shared__ __align__(16) f16 sAh[TM * 32];
    __shared__ __align__(16) f16 sAl[TM * 32];
    __shared__ __align__(16) f16 sBh[TN * 32];
    __shared__ __align__(16) f16 sBl[TN * 32];
    int tid = threadIdx.x;
    int wave = tid >> 6, lane = tid & 63;
    int wm = wave >> 1, wn = wave & 1;
    int quad = lane >> 4, l15 = lane & 15;
    int m0 = blockIdx.y * TM, n0 = blockIdx.x * TN;

    f32x4 acc[MF][NF];
    #pragma unroll
    for (int i = 0; i < MF; i++)
        #pragma unroll
        for (int j = 0; j < NF; j++)
            acc[i][j] = (f32x4){0.f, 0.f, 0.f, 0.f};

    size_t aoff = (size_t)(m0 + wave * (TM / 4) + (lane >> 2)) * K + (lane & 3) * 8;
    size_t boff = (size_t)(n0 + wave * (TN / 4) + (lane >> 2)) * K + (lane & 3) * 8;
    const f16* gAh = Ah + aoff;  const f16* gAl = Al + aoff;
    const f16* gBh = Bh + boff;  const f16* gBl = Bl + boff;
    f16* lAh = sAh + (wave * (TM / 4)) * 32;
    f16* lAl = sAl + (wave * (TM / 4)) * 32;
    f16* lBh = sBh + (wave * (TN / 4)) * 32;
    f16* lBl = sBl + (wave * (TN / 4)) * 32;
    const size_t rstep = (size_t)16 * K;

    #define GLL(g, l) __builtin_amdgcn_global_load_lds( \
        (const __attribute__((address_space(1))) void*)(g), \
        (__attribute__((address_space(3))) void*)(l), 16, 0, 0)

    for (int k0 = 0; k0 < K; k0 += 32) {
        #pragma unroll
        for (int i = 0; i < AI; i++) {
            GLL(gAh + i * rstep, lAh + i * 16 * 32);
            GLL(gAl + i * rstep, lAl + i * 16 * 32);
        }
        #pragma unroll
        for (int i = 0; i < BI; i++) {
            GLL(gBh + i * rstep, lBh + i * 16 * 32);
            GLL(gBl + i * rstep, lBl + i * 16 * 32);
        }
        gAh += 32; gAl += 32; gBh += 32; gBl += 32;
        __syncthreads();
        f16x8 ah[MF], al[MF], bh[NF], bl[NF];
        #pragma unroll
        for (int mt = 0; mt < MF; mt++) {
            int r = (wm * (TM / 2) + mt * 16 + l15) * 32 + quad * 8;
            ah[mt] = *(const f16x8*)&sAh[r];
            al[mt] = *(const f16x8*)&sAl[r];
        }
        #pragma unroll
        for (int nt = 0; nt < NF; nt++) {
            int r = (wn * (TN / 2) + nt * 16 + l15) * 32 + quad * 8;
            bh[nt] = *(const f16x8*)&sBh[r];
            bl[nt] = *(const f16x8*)&sBl[r];
        }
        #pragma unroll
        for (int mt = 0; mt < MF; mt++)
            #pragma unroll
            for (int nt = 0; nt < NF; nt++) {
                acc[mt][nt] = __builtin_amdgcn_mfma_f32_16x16x32_f16(al[mt], bh[nt], acc[mt][nt], 0, 0, 0);
                acc[mt][nt] = __builtin_amdgcn_mfma_f32_16x16x32_f16(ah[mt], bl[nt], acc[mt][nt], 0, 0, 0);
                acc[mt][nt] = __builtin_amdgcn_mfma_f32_16x16x32_f16(ah[mt], bh[nt], acc[mt][nt], 0, 0, 0);
            }
        __syncthreads();
    }
    #undef GLL

    // epilogue: D col = lane&15 (n), row = quad*4 + reg (m)
    #pragma unroll
    for (int nt = 0; nt < NF; nt++) {
        int gcol = n0 + wn * (TN / 2) + nt * 16 + l15;
        float bv = bias[gcol];
        #pragma unroll
        for (int mt = 0; mt < MF; mt++) {
            int grow = m0 + wm * (TM / 2) + mt * 16 + quad * 4;
            #pragma unroll
            for (int r = 0; r < 4; r++) {
                size_t off = (size_t)(grow + r) * N + gcol;
                float v = acc[mt][nt][r] + bv;
                if (MODE == 0) {
                    v = 0.5f * v * (1.0f + erff(v * 0.70710678118654752f));
                    f16 h, l; split2(v, h, l);
                    ((f16*)C0)[off] = h;
                    ((f16*)C1)[off] = l;
                } else {
                    ((float*)C0)[off] = res[off] + v;
                }
            }
        }
    }
}

// ---------- scores[r,m] = h_new[r,:] @ W_comp[:,m] + b_comp[m] ----------
__global__ __launch_bounds__(256)
void scores_kernel(const float* __restrict__ h, const float* __restrict__ Wc,
                   const float* __restrict__ bc, float* __restrict__ scores) {
    int row = blockIdx.x;
    int t = threadIdx.x;
    float acc[Mn] = {};
    const float* hr = h + (size_t)row * Dn;
    for (int d = t; d < Dn; d += 256) {
        float hv = hr[d];
        const float* w = Wc + (size_t)d * Mn;
        #pragma unroll
        for (int m = 0; m < Mn; m++) acc[m] += hv * w[m];
    }
    __shared__ float red[Mn][4];
    int wave = t >> 6, lane = t & 63;
    #pragma unroll
    for (int m = 0; m < Mn; m++) {
        float v = acc[m];
        #pragma unroll
        for (int off = 32; off; off >>= 1) v += __shfl_down(v, off);
        if (lane == 0) red[m][wave] = v;
    }
    __syncthreads();
    if (t < Mn) {
        float v = red[t][0] + red[t][1] + red[t][2] + red[t][3];
        scores[(size_t)row * Mn + t] = v + bc[t];
    }
}

// ---------- softmax over L (axis=1) per (b,m) ----------
__global__ __launch_bounds__(256)
void softmaxL_kernel(const float* __restrict__ scores, float* __restrict__ wL) {
    __shared__ float sb[4];
    int b = blockIdx.x / Mn, m = blockIdx.x % Mn;
    int t = threadIdx.x;
    const float* s = scores + (size_t)b * Ln * Mn + m;
    float mx = -INFINITY;
    for (int l = t; l < Ln; l += 256) mx = fmaxf(mx, s[(size_t)l * Mn]);
    mx = bmax(mx, sb);
    float z = 0.f;
    for (int l = t; l < Ln; l += 256) z += expf(s[(size_t)l * Mn] - mx);
    z = bsum(z, sb);
    float inv = 1.0f / z;
    float* w = wL + (size_t)b * Ln * Mn + m;
    for (int l = t; l < Ln; l += 256) w[(size_t)l * Mn] = expf(s[(size_t)l * Mn] - mx) * inv;
}

// ---------- memory partials: mpart[lc][b][m][d] = sum_{l in chunk lc} wL[b,l,m]*h[b,l,d] ----------
__global__ __launch_bounds__(256)
void memory_kernel(const float* __restrict__ h, const float* __restrict__ wL,
                   float* __restrict__ mpart) {
    int bid = blockIdx.x;                 // Bn * (Dn/256) * (Ln/512) = 128 blocks
    int lc = bid & 7;
    int dc = (bid >> 3) & 3;
    int b  = bid >> 5;
    int t = threadIdx.x;
    int d = dc * 256 + t;
    int l0 = lc * 512;
    float acc[Mn] = {};
    const float* hp = h + ((size_t)b * Ln + l0) * Dn + d;
    const float* wp = wL + ((size_t)b * Ln + l0) * Mn;
    for (int l = 0; l < 512; l++) {
        float hv = hp[(size_t)l * Dn];
        float4 w0 = *(const float4*)(wp + (size_t)l * Mn);
        float4 w1 = *(const float4*)(wp + (size_t)l * Mn + 4);
        acc[0] += w0.x * hv; acc[1] += w0.y * hv; acc[2] += w0.z * hv; acc[3] += w0.w * hv;
        acc[4] += w1.x * hv; acc[5] += w1.y * hv; acc[6] += w1.z * hv; acc[7] += w1.w * hv;
    }
    #pragma unroll
    for (int m = 0; m < Mn; m++)
        mpart[(((size_t)lc * Bn + b) * Mn + m) * Dn + d] = acc[m];
}

// ---------- reduce partials: mem[b][m][d] = sum_lc mpart[lc][b][m][d] ----------
__global__ __launch_bounds__(256)
void memreduce_kernel(const float* __restrict__ mpart, float* __restrict__ mem) {
    int i = blockIdx.x * 256 + threadIdx.x;   // over Bn*Mn*Dn = 32768
    float s = 0.f;
    #pragma unroll
    for (int lc = 0; lc < 8; lc++) s += mpart[(size_t)lc * Bn * Mn * Dn + i];
    mem[i] = s;
}

// ---------- ctx chunk (f16 split) = sum_m softmax_M(scores[r,:])[m] * memory[b,m,d] ----------
__global__ __launch_bounds__(256)
void ctx_kernel(const float* __restrict__ scores, const float* __restrict__ mem,
                f16* __restrict__ ch, f16* __restrict__ cl, int bidx) {
    int row = blockIdx.x;     // local to chunk
    int t = threadIdx.x;
    const float* s = scores + (size_t)row * Mn;
    float sm[Mn];
    float mx = -INFINITY;
    #pragma unroll
    for (int m = 0; m < Mn; m++) mx = fmaxf(mx, s[m]);
    float z = 0.f;
    #pragma unroll
    for (int m = 0; m < Mn; m++) { sm[m] = expf(s[m] - mx); z += sm[m]; }
    float inv = 1.0f / z;
    float acc[4] = {0.f, 0.f, 0.f, 0.f};
    #pragma unroll
    for (int m = 0; m < Mn; m++) {
        float w = sm[m] * inv;
        float4 mv = ((const float4*)(mem + ((size_t)bidx * Mn + m) * Dn))[t];
        acc[0] += w * mv.x; acc[1] += w * mv.y; acc[2] += w * mv.z; acc[3] += w * mv.w;
    }
    f16x4 oh, ol;
    #pragma unroll
    for (int i = 0; i < 4; i++) { f16 hh, ll; split2(acc[i], hh, ll); oh[i] = hh; ol[i] = ll; }
    *(f16x4*)(ch + (size_t)row * Dn + t * 4) = oh;
    *(f16x4*)(cl + (size_t)row * Dn + t * 4) = ol;
}

// ---------- entropy gate + ACT halting; hidden <- selected h_new; acc bf16 ----------
__global__ __launch_bounds__(256)
void gate_halt_kernel(const float* __restrict__ h_new, float* __restrict__ hidden,
                      const float* __restrict__ ent, const float* __restrict__ Wh,
                      const float* __restrict__ bh, bfu* __restrict__ acc,
                      float* __restrict__ cum) {
    __shared__ float sb[4];
    int row = blockIdx.x;
    int t = threadIdx.x;
    bool upd = ent[row] > THRc;
    const float* src = (upd ? h_new : hidden) + (size_t)row * Dn;
    float4 hv = ((const float4*)src)[t];
    float4 wv = ((const float4*)Wh)[t];
    float dot = hv.x*wv.x + hv.y*wv.y + hv.z*wv.z + hv.w*wv.w;
    dot = bsum(dot, sb);
    float p = 1.0f / (1.0f + expf(-(dot + bh[0])));
    float c = cum[row];
    float w = p * (1.0f - c);
    ushort4 a = *(ushort4*)(acc + (size_t)row * Dn + t * 4);
    ushort4 o;
    o.x = f2b(b2f(a.x) + w * hv.x);
    o.y = f2b(b2f(a.y) + w * hv.y);
    o.z = f2b(b2f(a.z) + w * hv.z);
    o.w = f2b(b2f(a.w) + w * hv.w);
    *(ushort4*)(acc + (size_t)row * Dn + t * 4) = o;
    ((float4*)(hidden + (size_t)row * Dn))[t] = hv;
    __syncthreads();                 // all waves read cum[row] before lane0 overwrites it
    if (t == 0) cum[row] = c + w;
}

// ---------- final: out = LN(acc + (1-cum)*hidden, g2, b2) ----------
__global__ __launch_bounds__(256)
void final_ln_kernel(const bfu* __restrict__ acc, const float* __restrict__ cum,
                     const float* __restrict__ hidden,
                     const float* __restrict__ g2, const float* __restrict__ b2,
                     float* __restrict__ out) {
    __shared__ float sb[4];
    int row = blockIdx.x;
    int t = threadIdx.x;
    float c = 1.0f - cum[row];
    ushort4 a = *(const ushort4*)(acc + (size_t)row * Dn + t * 4);
    float4 h = ((const float4*)(hidden + (size_t)row * Dn))[t];
    float vals[4];
    vals[0] = b2f(a.x) + c * h.x; vals[1] = b2f(a.y) + c * h.y;
    vals[2] = b2f(a.z) + c * h.z; vals[3] = b2f(a.w) + c * h.w;
    float s = 0.f, s2 = 0.f;
    #pragma unroll
    for (int i = 0; i < 4; i++) { s += vals[i]; s2 += vals[i]*vals[i]; }
    s  = bsum(s,  sb);
    s2 = bsum(s2, sb);
    float mean = s * (1.f / Dn);
    float var  = s2 * (1.f / Dn) - mean * mean;
    float rstd = rsqrtf(var + EPSc);
    float4 g = ((const float4*)g2)[t];
    float4 bb = ((const float4*)b2)[t];
    float4 o;
    o.x = (vals[0] - mean) * rstd * g.x + bb.x;
    o.y = (vals[1] - mean) * rstd * g.y + bb.y;
    o.z = (vals[2] - mean) * rstd * g.z + bb.z;
    o.w = (vals[3] - mean) * rstd * g.w + bb.w;
    ((float4*)(out + (size_t)row * Dn))[t] = o;
}

extern "C" void kernel_launch(void* const* d_in, const int* in_sizes, int n_in,
                              void* d_out, int out_size, void* d_ws, size_t ws_size,
                              hipStream_t stream) {
    (void)in_sizes; (void)n_in; (void)out_size; (void)ws_size;
    const float* x      = (const float*)d_in[0];
    const float* g1     = (const float*)d_in[1];
    const float* b1     = (const float*)d_in[2];
    const float* W_up   = (const float*)d_in[3];
    const float* b_up   = (const float*)d_in[4];
    const float* W_down = (const float*)d_in[5];
    const float* b_down = (const float*)d_in[6];
    const float* W_halt = (const float*)d_in[7];
    const float* b_halt = (const float*)d_in[8];
    const float* W_comp = (const float*)d_in[9];
    const float* b_comp = (const float*)d_in[10];
    const float* W_attn = (const float*)d_in[11];
    const float* b_attn = (const float*)d_in[12];
    const float* g2     = (const float*)d_in[13];
    const float* b2     = (const float*)d_in[14];
    float* out = (float*)d_out;

    // ws layout — ~248 MB total (≤ round-4's memory-clean 264.5 MB)
    char* wsb = (char*)d_ws;
    size_t off = 0;
    float* hidden = (float*)(wsb + off); off += (size_t)Rn * Dn * 4;      // 67.1 MB
    float* hnew   = (float*)(wsb + off); off += (size_t)Rn * Dn * 4;      // 67.1 MB
    bfu*   accb   = (bfu*)  (wsb + off); off += (size_t)Rn * Dn * 2;      // 33.6 MB (bf16)
    f16*   nh     = (f16*)  (wsb + off); off += (size_t)CHUNK * Dn * 2;   //  4.2 MB
    f16*   nl     = (f16*)  (wsb + off); off += (size_t)CHUNK * Dn * 2;   //  4.2 MB
    f16*   uh     = (f16*)  (wsb + off); off += (size_t)CHUNK * DIn * 2;  // 16.8 MB
    f16*   ul     = (f16*)  (wsb + off); off += (size_t)CHUNK * DIn * 2;  // 16.8 MB
    f16*   WupTh  = (f16*)  (wsb + off); off += (size_t)DIn * Dn * 2;     //  8.4 MB
    f16*   WupTl  = (f16*)  (wsb + off); off += (size_t)DIn * Dn * 2;     //  8.4 MB
    f16*   WdnTh  = (f16*)  (wsb + off); off += (size_t)Dn * DIn * 2;     //  8.4 MB
    f16*   WdnTl  = (f16*)  (wsb + off); off += (size_t)Dn * DIn * 2;     //  8.4 MB
    f16*   WatTh  = (f16*)  (wsb + off); off += (size_t)Dn * Dn * 2;      //  2.1 MB
    f16*   WatTl  = (f16*)  (wsb + off); off += (size_t)Dn * Dn * 2;      //  2.1 MB
    float* scores = (float*)(wsb + off); off += (size_t)Rn * Mn * 4;
    float* wL     = (float*)(wsb + off); off += (size_t)Rn * Mn * 4;
    float* mpart  = (float*)(wsb + off); off += (size_t)8 * Bn * Mn * Dn * 4;
    float* memb   = (float*)(wsb + off); off += (size_t)Bn * Mn * Dn * 4;
    float* ent    = (float*)(wsb + off); off += (size_t)Rn * 4;
    float* cum    = (float*)(wsb + off); off += (size_t)Rn * 4;
    f16*   ch = nh, *cl = nl;   // reuse: nh/nl dead after FFN chunk loop

    transpose_cvt_kernel<<<dim3(DIn / 32, Dn / 32), 256, 0, stream>>>(W_up,   WupTh, WupTl, Dn, DIn);
    transpose_cvt_kernel<<<dim3(Dn / 32, DIn / 32), 256, 0, stream>>>(W_down, WdnTh, WdnTl, DIn, Dn);
    transpose_cvt_kernel<<<dim3(Dn / 32, Dn / 32),  256, 0, stream>>>(W_attn, WatTh, WatTl, Dn, Dn);

    init_kernel<<<(Rn * Dn / 4) / 256, 256, 0, stream>>>(x, hidden, accb, cum);

    for (int s = 0; s < NSTEP; ++s) {
        for (int c = 0; c < NCH; ++c) {
            ln_ent_kernel<<<CHUNK, 256, 0, stream>>>(
                hidden + (size_t)c * CHUNK * Dn, g1, b1, nh, nl, ent + (size_t)c * CHUNK);
            gemm_f16s<0, 128, 128><<<dim3(DIn / 128, CHUNK / 128), 256, 0, stream>>>(
                nh, nl, WupTh, WupTl, b_up, nullptr, uh, ul, DIn, Dn);
            gemm_f16s<1, 128, 64><<<dim3(Dn / 64, CHUNK / 128), 256, 0, stream>>>(
                uh, ul, WdnTh, WdnTl, b_down, hidden + (size_t)c * CHUNK * Dn,
                hnew + (size_t)c * CHUNK * Dn, nullptr, Dn, DIn);
        }
        scores_kernel<<<Rn, 256, 0, stream>>>(hnew, W_comp, b_comp, scores);
        softmaxL_kernel<<<Bn * Mn, 256, 0, stream>>>(scores, wL);
        memory_kernel<<<Bn * (Dn / 256) * (Ln / 512), 256, 0, stream>>>(hnew, wL, mpart);
        memreduce_kernel<<<(Bn * Mn * Dn) / 256, 256, 0, stream>>>(mpart, memb);
        for (int c = 0; c < NCH; ++c) {
            ctx_kernel<<<CHUNK, 256, 0, stream>>>(
                scores + (size_t)c * CHUNK * Mn, memb, ch, cl, (c * CHUNK) / Ln);
            gemm_f16s<1, 128, 64><<<dim3(Dn / 64, CHUNK / 128), 256, 0, stream>>>(
                ch, cl, WatTh, WatTl, b_attn, hnew + (size_t)c * CHUNK * Dn,
                hnew + (size_t)c * CHUNK * Dn, nullptr, Dn, Dn);
        }
        gate_halt_kernel<<<Rn, 256, 0, stream>>>(hnew, hidden, ent, W_halt, b_halt, accb, cum);
    }

    final_ln_kernel<<<Rn, 256, 0, stream>>>(accb, cum, hidden, g2, b2, out);
}